// Round 4
// baseline (1469.982 us; speedup 1.0000x reference)
//
#include <hip/hip_runtime.h>
#include <hip/hip_bf16.h>

#define IN_DIM   4096
#define OUT_DIM  11008
#define M_DIM    8192

typedef __bf16 bf16x8 __attribute__((ext_vector_type(8)));
typedef float  f32x4  __attribute__((ext_vector_type(4)));

#define GLOBAL_AS __attribute__((address_space(1)))
#define LDS_AS    __attribute__((address_space(3)))

__device__ __forceinline__ void async_copy16(const void* g, void* l) {
    __builtin_amdgcn_global_load_lds((GLOBAL_AS void*)g, (LDS_AS void*)l, 16, 0, 0);
}

__device__ __forceinline__ ushort f2bf(float f) {
    __hip_bfloat16 h = __float2bfloat16(f);
    return *reinterpret_cast<ushort*>(&h);
}
__device__ __forceinline__ float bf2f(ushort u) {
    __hip_bfloat16 h;
    *reinterpret_cast<ushort*>(&h) = u;
    return __bfloat162float(h);
}

// ---------------------------------------------------------------------------
// K1: dequant 4-bit codes via per-row LUT -> W bf16 [OUT][IN]
// one thread per qweight word (out, iw): writes 8 consecutive bf16 (16B).
// ---------------------------------------------------------------------------
__global__ __launch_bounds__(256) void dequant_kernel(
        const int* __restrict__ qweight,      // [IN/8][OUT]
        const float* __restrict__ lut,        // [OUT][16]
        ushort* __restrict__ W) {             // [OUT][IN] bf16
    int tid = blockIdx.x * 256 + threadIdx.x;
    int out = tid >> 9;          // /512
    int iw  = tid & 511;
    int word = qweight[(size_t)iw * OUT_DIM + out];
    const float* lrow = lut + (size_t)out * 16;
    union { ushort s[8]; uint4 v; } u;
#pragma unroll
    for (int k = 0; k < 8; ++k) {
        int code = (word >> (k * 4)) & 0xF;
        u.s[k] = f2bf(lrow[code]);
    }
    *reinterpret_cast<uint4*>(&W[(size_t)out * IN_DIM + iw * 8]) = u.v;
}

// ---------------------------------------------------------------------------
// K2: CSR sparse corrections (outlier + sensitive), one thread per row.
// Serial within a row => duplicate (row,col) handled correctly, no atomics.
// ---------------------------------------------------------------------------
__global__ __launch_bounds__(256) void sparse_add_kernel(
        const int* __restrict__ o_rows, const int* __restrict__ o_cols, const float* __restrict__ o_vals,
        const int* __restrict__ s_rows, const int* __restrict__ s_cols, const float* __restrict__ s_vals,
        ushort* __restrict__ W) {
    int r = blockIdx.x * 256 + threadIdx.x;
    if (r >= OUT_DIM) return;
    ushort* wr = W + (size_t)r * IN_DIM;
    int e = o_rows[r + 1];
    for (int j = o_rows[r]; j < e; ++j) {
        int c = o_cols[j];
        wr[c] = f2bf(bf2f(wr[c]) + o_vals[j]);
    }
    e = s_rows[r + 1];
    for (int j = s_rows[r]; j < e; ++j) {
        int c = s_cols[j];
        wr[c] = f2bf(bf2f(wr[c]) + s_vals[j]);
    }
}

// ---------------------------------------------------------------------------
// K3: x fp32 -> bf16, 8 elements/thread, 16B stores.
// ---------------------------------------------------------------------------
__global__ __launch_bounds__(256) void cvt_kernel(
        const float* __restrict__ x, ushort* __restrict__ xb) {
    size_t t = (size_t)blockIdx.x * 256 + threadIdx.x;
    const float4* xp = reinterpret_cast<const float4*>(x);
    float4 a = xp[2 * t];
    float4 b = xp[2 * t + 1];
    union { ushort s[8]; uint4 v; } u;
    u.s[0] = f2bf(a.x); u.s[1] = f2bf(a.y); u.s[2] = f2bf(a.z); u.s[3] = f2bf(a.w);
    u.s[4] = f2bf(b.x); u.s[5] = f2bf(b.y); u.s[6] = f2bf(b.z); u.s[7] = f2bf(b.w);
    reinterpret_cast<uint4*>(xb)[t] = u.v;
}

// ---------------------------------------------------------------------------
// K4: GEMM  C[M][N] = A[M][K](bf16) * B[N][K](bf16)^T + bias
// m97 structure: 128x128 tile, BK=32, 4 waves (each 64x64 = 4x4 16x16 frags),
// global_load_lds width=16 staging, single LDS buffer, 2 barriers/K-step.
// ---------------------------------------------------------------------------
__global__ __launch_bounds__(256) void gemm_kernel(
        const ushort* __restrict__ A,      // [M][K] bf16
        const ushort* __restrict__ B,      // [N][K] bf16
        const float* __restrict__ bias,    // [N]
        float* __restrict__ C) {           // [M][N]
    __shared__ ushort As[128 * 32];
    __shared__ ushort Bs[128 * 32];

    // bijective XCD swizzle (gridDim.x = 5504 is a multiple of 8)
    const int nbx = OUT_DIM / 128;                 // 86
    int orig = blockIdx.x;
    int cpx  = gridDim.x >> 3;                     // 688
    int swz  = (orig & 7) * cpx + (orig >> 3);
    int bx = swz % nbx;
    int by = swz / nbx;
    const int m0 = by * 128;
    const int n0 = bx * 128;

    const int tid  = threadIdx.x;
    const int lane = tid & 63;
    const int w    = tid >> 6;
    const int wr   = w >> 1;       // wave row 0..1
    const int wc   = w & 1;        // wave col 0..1

    const int lrow = lane & 15;
    const int lhi  = lane >> 4;

    // staging geometry: wave w stages 32 rows of the tile (2 calls x 16 rows)
    const int srow  = w * 32 + (lane >> 2);
    const int skoff = (lane & 3) * 8;

    f32x4 acc[4][4] = {};

    for (int kt = 0; kt < IN_DIM; kt += 32) {
#pragma unroll
        for (int i = 0; i < 2; ++i) {
            int row = srow + i * 16;
            async_copy16(A + (size_t)(m0 + row) * IN_DIM + kt + skoff,
                         As + w * 1024 + i * 512);
            async_copy16(B + (size_t)(n0 + row) * IN_DIM + kt + skoff,
                         Bs + w * 1024 + i * 512);
        }
        __syncthreads();

        bf16x8 af[4], bfr[4];
#pragma unroll
        for (int mi = 0; mi < 4; ++mi)
            af[mi] = *reinterpret_cast<const bf16x8*>(
                &As[(wr * 64 + mi * 16 + lrow) * 32 + lhi * 8]);
#pragma unroll
        for (int ni = 0; ni < 4; ++ni)
            bfr[ni] = *reinterpret_cast<const bf16x8*>(
                &Bs[(wc * 64 + ni * 16 + lrow) * 32 + lhi * 8]);

#pragma unroll
        for (int mi = 0; mi < 4; ++mi)
#pragma unroll
            for (int ni = 0; ni < 4; ++ni)
                acc[mi][ni] = __builtin_amdgcn_mfma_f32_16x16x32_bf16(
                    af[mi], bfr[ni], acc[mi][ni], 0, 0, 0);
        __syncthreads();
    }

    // epilogue: C/D layout col = lane&15, row = (lane>>4)*4 + j
#pragma unroll
    for (int ni = 0; ni < 4; ++ni) {
        int col = n0 + wc * 64 + ni * 16 + lrow;
        float bv = bias[col];
#pragma unroll
        for (int mi = 0; mi < 4; ++mi) {
            int rbase = m0 + wr * 64 + mi * 16 + lhi * 4;
#pragma unroll
            for (int j = 0; j < 4; ++j) {
                C[(size_t)(rbase + j) * OUT_DIM + col] = acc[mi][ni][j] + bv;
            }
        }
    }
}

// ---------------------------------------------------------------------------
extern "C" void kernel_launch(void* const* d_in, const int* in_sizes, int n_in,
                              void* d_out, int out_size, void* d_ws, size_t ws_size,
                              hipStream_t stream) {
    const float* x        = (const float*)d_in[0];
    const int*   qweight  = (const int*)d_in[1];
    const float* lut      = (const float*)d_in[2];
    const float* bias     = (const float*)d_in[3];
    const int*   o_rows   = (const int*)d_in[4];
    const int*   o_cols   = (const int*)d_in[5];
    const float* o_vals   = (const float*)d_in[6];
    const int*   s_rows   = (const int*)d_in[7];
    const int*   s_cols   = (const int*)d_in[8];
    const float* s_vals   = (const float*)d_in[9];
    float* out = (float*)d_out;

    ushort* W  = (ushort*)d_ws;                                   // 90,177,536 B
    ushort* Xb = (ushort*)((char*)d_ws + (size_t)OUT_DIM * IN_DIM * 2);

    // K1: dequant (OUT*IN/8 words, 1 thread each)
    dequant_kernel<<<dim3(OUT_DIM * 512 / 256), dim3(256), 0, stream>>>(qweight, lut, W);
    // K2: sparse corrections
    sparse_add_kernel<<<dim3((OUT_DIM + 255) / 256), dim3(256), 0, stream>>>(
        o_rows, o_cols, o_vals, s_rows, s_cols, s_vals, W);
    // K3: x -> bf16
    cvt_kernel<<<dim3((M_DIM * IN_DIM / 8) / 256), dim3(256), 0, stream>>>(x, Xb);
    // K4: GEMM
    gemm_kernel<<<dim3((M_DIM / 128) * (OUT_DIM / 128)), dim3(256), 0, stream>>>(
        Xb, W, bias, out);
}